// Round 11
// baseline (171.354 us; speedup 1.0000x reference)
//
#include <hip/hip_runtime.h>
#include <hip/hip_bf16.h>

#define BB 2
#define TT 2048
#define CCH 1024
#define NHH 16
#define HDD 64
#define M_TOK (BB*TT)      // 4096
#define N_QKV (3*CCH)      // 3072

typedef __attribute__((ext_vector_type(8))) short bf16x8;
typedef __attribute__((ext_vector_type(4))) float f32x4;
typedef unsigned short u16;
typedef unsigned int u32;

__device__ __forceinline__ u16 f2bf(float f) {
    union { float f; u32 u; } v; v.f = f;
    u32 u = v.u;
    u32 r = (u + 0x7FFFu + ((u >> 16) & 1u)) >> 16;
    return (u16)r;
}

// pack hi16(a),hi16(b) -> u32 {b.hi<<16 | a.hi} with +0x8000 rounding
__device__ __forceinline__ u32 pk_bf16(float a, float b) {
    u32 ua = __float_as_uint(a) + 0x8000u;
    u32 ub = __float_as_uint(b) + 0x8000u;
    return __builtin_amdgcn_perm(ub, ua, 0x07060302u);
}

__device__ __forceinline__ void async_copy16(const void* g, void* l) {
    __builtin_amdgcn_global_load_lds((__attribute__((address_space(1))) void*)g,
                                     (__attribute__((address_space(3))) void*)l,
                                     16, 0, 0);
}

// ---------------- pre-pass kernels ----------------

__global__ __launch_bounds__(256) void cast_bf16_kernel(
    const float* __restrict__ src, u16* __restrict__ dst, int n4) {
    int i = blockIdx.x * 256 + threadIdx.x;
    if (i < n4) {
        float4 f = ((const float4*)src)[i];
        ushort4 o;
        o.x = f2bf(f.x); o.y = f2bf(f.y); o.z = f2bf(f.z); o.w = f2bf(f.w);
        ((ushort4*)dst)[i] = o;
    }
}

// src [R][Cn] fp32 -> dst [Cn][R] bf16; rows of dst with index < scale_rows get *= sc
__global__ __launch_bounds__(256) void transpose_bf16_kernel(
    const float* __restrict__ src, u16* __restrict__ dst, int R, int Cn,
    int scale_rows, float sc) {
    __shared__ float tile[32][33];
    int c0 = blockIdx.x * 32, r0 = blockIdx.y * 32;
    int tx = threadIdx.x, ty = threadIdx.y;
#pragma unroll
    for (int i = ty; i < 32; i += 8)
        tile[i][tx] = src[(size_t)(r0 + i) * Cn + c0 + tx];
    __syncthreads();
#pragma unroll
    for (int i = ty; i < 32; i += 8) {
        float v = tile[tx][i];
        if (c0 + i < scale_rows) v *= sc;
        dst[(size_t)(c0 + i) * R + r0 + tx] = f2bf(v);
    }
}

// ---------------- QKV GEMM v2: 256x192 tiles, counted-vmcnt pipeline (R7 WIN) ----------------

#define QKV_NK 16            // K / 64
#define QKV_AS_HALF 16384    // 256*64 u16
#define QKV_BS_HALF 12288    // 192*64 u16
#define QKV_SMEM_BYTES ((2*QKV_AS_HALF + 2*QKV_BS_HALF) * 2)   // 114688

__global__ __launch_bounds__(512, 1) void qkv_gemm_kernel(
    const u16* __restrict__ A, const u16* __restrict__ Bt,
    u16* __restrict__ Qo, u16* __restrict__ Ko, u16* __restrict__ Vto)
{
    extern __shared__ __align__(16) u16 smem[];
    u16* AsB = smem;                       // 2 x 256*64
    u16* BsB = smem + 2 * QKV_AS_HALF;     // 2 x 192*64
    int t = threadIdx.x;
    int lane = t & 63, w = t >> 6;
    int m0 = blockIdx.y * 256, n0 = blockIdx.x * 192;
    int mw = (w >> 1) * 64, nw = (w & 1) * 96;
    int mr = lane & 15, quad = lane >> 4, swm = mr & 7;

    f32x4 zero = {0.f, 0.f, 0.f, 0.f};
    f32x4 acc[4][6];
#pragma unroll
    for (int i = 0; i < 4; ++i)
#pragma unroll
        for (int j = 0; j < 6; ++j) acc[i][j] = zero;

    // staging geometry (verified pattern: 8 lanes/row, chunk c stored at c^(row&7))
    int lr = lane >> 3;
    int cswz = (lane & 7) ^ lr;
    const u16* gA[4]; int lAo[4];
#pragma unroll
    for (int p = 0; p < 4; ++p) {
        int grp = w * 4 + p;               // 32 groups x 8 rows = 256
        gA[p] = A + (size_t)(m0 + grp * 8 + lr) * CCH + cswz * 8;
        lAo[p] = (grp * 64 + lane) * 8;
    }
    const u16* gB[3]; int lBo[3];
#pragma unroll
    for (int p = 0; p < 3; ++p) {
        int grp = w * 3 + p;               // 24 groups x 8 rows = 192
        gB[p] = Bt + (size_t)(n0 + grp * 8 + lr) * CCH + cswz * 8;
        lBo[p] = (grp * 64 + lane) * 8;
    }

#define QKV_STAGE(K0, BUF) do {                                               \
    u16* dA_ = AsB + (BUF) * QKV_AS_HALF;                                     \
    u16* dB_ = BsB + (BUF) * QKV_BS_HALF;                                     \
    _Pragma("unroll") for (int p_ = 0; p_ < 4; ++p_)                          \
        async_copy16(gA[p_] + (K0), dA_ + lAo[p_]);                           \
    _Pragma("unroll") for (int p_ = 0; p_ < 3; ++p_)                          \
        async_copy16(gB[p_] + (K0), dB_ + lBo[p_]);                           \
  } while (0)

    // prologue: tiles 0 and 1 in flight (14 loads outstanding)
    QKV_STAGE(0, 0);
    QKV_STAGE(64, 1);

    for (int k = 0; k < QKV_NK; ++k) {
        int cur = k & 1;
        if (k == QKV_NK - 1) asm volatile("s_waitcnt vmcnt(0)" ::: "memory");
        else                 asm volatile("s_waitcnt vmcnt(7)" ::: "memory");
        __builtin_amdgcn_s_barrier();      // all waves: tile k fully staged
        asm volatile("" ::: "memory");
        const u16* Ac = AsB + cur * QKV_AS_HALF;
        const u16* Bc = BsB + cur * QKV_BS_HALF;
        bf16x8 a0[4], a1[4], b0[6], b1[6];
#pragma unroll
        for (int i = 0; i < 4; ++i) {
            int r = (mw + i * 16 + mr) * 64;
            a0[i] = *(const bf16x8*)&Ac[r + ((quad ^ swm) << 3)];
            a1[i] = *(const bf16x8*)&Ac[r + (((quad + 4) ^ swm) << 3)];
        }
#pragma unroll
        for (int j = 0; j < 6; ++j) {
            int r = (nw + j * 16 + mr) * 64;
            b0[j] = *(const bf16x8*)&Bc[r + ((quad ^ swm) << 3)];
            b1[j] = *(const bf16x8*)&Bc[r + (((quad + 4) ^ swm) << 3)];
        }
#pragma unroll
        for (int i = 0; i < 4; ++i)
#pragma unroll
            for (int j = 0; j < 6; ++j)
                acc[i][j] = __builtin_amdgcn_mfma_f32_16x16x32_bf16(b0[j], a0[i], acc[i][j], 0, 0, 0);
        asm volatile("s_waitcnt lgkmcnt(0)" ::: "memory");
        __builtin_amdgcn_sched_barrier(0);
        __builtin_amdgcn_s_barrier();      // all waves done reading buf cur
        asm volatile("" ::: "memory");
        if (k < QKV_NK - 2) QKV_STAGE((k + 2) * 64, cur);  // WAR-safe overwrite
#pragma unroll
        for (int i = 0; i < 4; ++i)
#pragma unroll
            for (int j = 0; j < 6; ++j)
                acc[i][j] = __builtin_amdgcn_mfma_f32_16x16x32_bf16(b1[j], a1[i], acc[i][j], 0, 0, 0);
    }
#undef QKV_STAGE

    // epilogue: C^T fragments; part decided per 16-col fragment (wave-uniform)
#pragma unroll
    for (int i = 0; i < 4; ++i)
#pragma unroll
        for (int j = 0; j < 6; ++j) {
            int tok = m0 + mw + i * 16 + mr;
            int cg0 = n0 + nw + j * 16 + quad * 4;
            int part = cg0 >> 10;
            int cc = cg0 & 1023;
            int h = cc >> 6, d0 = cc & 63;
            int b = tok >> 11, tt = tok & 2047;
            int bh = b * NHH + h;
            if (part < 2) {
                u16* dstp = part ? Ko : Qo;
                uint2 o;
                o.x = pk_bf16(acc[i][j][0], acc[i][j][1]);
                o.y = pk_bf16(acc[i][j][2], acc[i][j][3]);
                *(uint2*)&dstp[((size_t)bh * TT + tt) * HDD + d0] = o;
            } else {
#pragma unroll
                for (int r = 0; r < 4; ++r)
                    Vto[((size_t)bh * HDD + d0 + r) * TT + tt] = f2bf(acc[i][j][r]);
            }
        }
}

// ---------------- proj GEMM v2: 128x128 tiles, counted-vmcnt pipeline (R8 WIN) ----------------

#define PRJ_NK 16            // K / 64
#define PRJ_AS_HALF 8192     // 128*64 u16
#define PRJ_SMEM_BYTES (4 * PRJ_AS_HALF * 2)   // 65536

__global__ __launch_bounds__(512, 1) void proj_gemm_kernel(
    const u16* __restrict__ A, const u16* __restrict__ Bt, float* __restrict__ Cout)
{
    extern __shared__ __align__(16) u16 psmem[];
    u16* AsB = psmem;                      // 2 x 128*64
    u16* BsB = psmem + 2 * PRJ_AS_HALF;    // 2 x 128*64
    int t = threadIdx.x;
    int lane = t & 63, w = t >> 6;
    int m0 = blockIdx.y * 128, n0 = blockIdx.x * 128;
    int mw = (w >> 1) * 32, nw = (w & 1) * 64;
    int mr = lane & 15, quad = lane >> 4, swm = mr & 7;

    f32x4 zero = {0.f, 0.f, 0.f, 0.f};
    f32x4 acc[2][4];
#pragma unroll
    for (int i = 0; i < 2; ++i)
#pragma unroll
        for (int j = 0; j < 4; ++j) acc[i][j] = zero;

    int lr = lane >> 3;
    int cswz = (lane & 7) ^ lr;
    const u16* gA[2]; int lAo[2];
#pragma unroll
    for (int p = 0; p < 2; ++p) {
        int grp = w * 2 + p;               // 16 groups x 8 rows = 128
        gA[p] = A + (size_t)(m0 + grp * 8 + lr) * CCH + cswz * 8;
        lAo[p] = (grp * 64 + lane) * 8;
    }
    const u16* gB[2]; int lBo[2];
#pragma unroll
    for (int p = 0; p < 2; ++p) {
        int grp = w * 2 + p;               // 16 groups x 8 rows = 128
        gB[p] = Bt + (size_t)(n0 + grp * 8 + lr) * CCH + cswz * 8;
        lBo[p] = (grp * 64 + lane) * 8;
    }

#define PRJ_STAGE(K0, BUF) do {                                               \
    u16* dA_ = AsB + (BUF) * PRJ_AS_HALF;                                     \
    u16* dB_ = BsB + (BUF) * PRJ_AS_HALF;                                     \
    _Pragma("unroll") for (int p_ = 0; p_ < 2; ++p_)                          \
        async_copy16(gA[p_] + (K0), dA_ + lAo[p_]);                           \
    _Pragma("unroll") for (int p_ = 0; p_ < 2; ++p_)                          \
        async_copy16(gB[p_] + (K0), dB_ + lBo[p_]);                           \
  } while (0)

    PRJ_STAGE(0, 0);
    PRJ_STAGE(64, 1);

    for (int k = 0; k < PRJ_NK; ++k) {
        int cur = k & 1;
        if (k == PRJ_NK - 1) asm volatile("s_waitcnt vmcnt(0)" ::: "memory");
        else                 asm volatile("s_waitcnt vmcnt(4)" ::: "memory");
        __builtin_amdgcn_s_barrier();      // tile k fully staged
        asm volatile("" ::: "memory");
        const u16* Ac = AsB + cur * PRJ_AS_HALF;
        const u16* Bc = BsB + cur * PRJ_AS_HALF;
        bf16x8 a0[2], a1[2], b0[4], b1[4];
#pragma unroll
        for (int i = 0; i < 2; ++i) {
            int r = (mw + i * 16 + mr) * 64;
            a0[i] = *(const bf16x8*)&Ac[r + ((quad ^ swm) << 3)];
            a1[i] = *(const bf16x8*)&Ac[r + (((quad + 4) ^ swm) << 3)];
        }
#pragma unroll
        for (int j = 0; j < 4; ++j) {
            int r = (nw + j * 16 + mr) * 64;
            b0[j] = *(const bf16x8*)&Bc[r + ((quad ^ swm) << 3)];
            b1[j] = *(const bf16x8*)&Bc[r + (((quad + 4) ^ swm) << 3)];
        }
#pragma unroll
        for (int i = 0; i < 2; ++i)
#pragma unroll
            for (int j = 0; j < 4; ++j)
                acc[i][j] = __builtin_amdgcn_mfma_f32_16x16x32_bf16(b0[j], a0[i], acc[i][j], 0, 0, 0);
        asm volatile("s_waitcnt lgkmcnt(0)" ::: "memory");
        __builtin_amdgcn_sched_barrier(0);
        __builtin_amdgcn_s_barrier();      // all waves done reading buf cur
        asm volatile("" ::: "memory");
        if (k < PRJ_NK - 2) PRJ_STAGE((k + 2) * 64, cur);
#pragma unroll
        for (int i = 0; i < 2; ++i)
#pragma unroll
            for (int j = 0; j < 4; ++j)
                acc[i][j] = __builtin_amdgcn_mfma_f32_16x16x32_bf16(b1[j], a1[i], acc[i][j], 0, 0, 0);
    }
#undef PRJ_STAGE

    // epilogue: C^T fragments (tok on lane&15), float4 stores
#pragma unroll
    for (int i = 0; i < 2; ++i)
#pragma unroll
        for (int j = 0; j < 4; ++j) {
            int tok = m0 + mw + i * 16 + mr;
            int cg0 = n0 + nw + j * 16 + quad * 4;
            float4 v;
            v.x = acc[i][j][0]; v.y = acc[i][j][1];
            v.z = acc[i][j][2]; v.w = acc[i][j][3];
            *(float4*)&Cout[(size_t)tok * CCH + cg0] = v;
        }
}

// ---------------- flash attention v18: cross-tile P-roundtrip pipelining ----------------
// R10: T4 counted-vmcnt NULLED -> load latency not the stall. Per-wave issue
// density ~11%: waves stall on intra-iteration dependency chains. The longest
// strictly-serial segment left is the P LDS roundtrip (write -> read -> PV).
// v18 splits tile3 into tile_qk (QK+exp+P-write) and tile_pv (PV from an
// explicit pf register) and orders each 2-tile iteration as:
//   qk_A -> load pfA -> qk_B -> pv_A(pfA) -> load pfB -> pv_B(pfB)
// so pfA's ~140cy read latency hides under qk_B's MFMA+exp2 issue and pfB's
// under pv_A's MFMAs. Pure reordering: pbA/pbB disjoint, per-wave DS in-order
// guarantees read-after-own-write. Triple-buffer staging kept from v17.

#define PST2 40   // P row stride (u16): 16B-aligned rows

template<bool MASK>
__device__ __forceinline__ void tile_qk(
    const u16* __restrict__ Kb, u16* __restrict__ pb,
    bf16x8 qf0, bf16x8 qf1, int m, int quad, int sw, int kh,
    int kvb, int qcol)
{
    f32x4 zero = {0.f, 0.f, 0.f, 0.f};
#pragma unroll
    for (int kc = 0; kc < 2; ++kc) {
        int rr = kh * 32 + kc * 16 + m;
        bf16x8 kf0 = *(const bf16x8*)&Kb[rr * 64 + ((quad ^ sw) << 3)];
        bf16x8 kf1 = *(const bf16x8*)&Kb[rr * 64 + (((quad + 4) ^ sw) << 3)];
        // S^T: kv = kvb + kc*16 + quad*4 + r (rows), q = qcol (cols)
        f32x4 s  = __builtin_amdgcn_mfma_f32_16x16x32_bf16(kf0, qf0, zero, 0, 0, 0);
        f32x4 st = __builtin_amdgcn_mfma_f32_16x16x32_bf16(kf1, qf1, s, 0, 0, 0);
        float e0, e1, e2, e3;
#pragma unroll
        for (int r = 0; r < 4; ++r) {
            float v = st[r];
            if (MASK && (kvb + kc * 16 + quad * 4 + r > qcol)) v = -1e30f;
            float e = __builtin_amdgcn_exp2f(v);
            if (r == 0) e0 = e; else if (r == 1) e1 = e; else if (r == 2) e2 = e; else e3 = e;
        }
        uint2 pk; pk.x = pk_bf16(e0, e1); pk.y = pk_bf16(e2, e3);
        *(uint2*)&pb[m * PST2 + kc * 16 + quad * 4] = pk;
    }
}

__device__ __forceinline__ bf16x8 load_pf(const u16* __restrict__ pb, int m, int quad) {
    return *(const bf16x8*)&pb[m * PST2 + quad * 8];
}

__device__ __forceinline__ void tile_pv(
    const u16* __restrict__ Vb, bf16x8 pf, bf16x8 ones,
    int m, int quad, int sw, int kh, f32x4 (&o)[4], f32x4& lacc)
{
    // l-row-sum rides the MFMA pipe (P.1)
    lacc = __builtin_amdgcn_mfma_f32_16x16x32_bf16(ones, pf, lacc, 0, 0, 0);
#pragma unroll
    for (int dg = 0; dg < 4; ++dg) {
        int rr = dg * 16 + m;
        bf16x8 vf = *(const bf16x8*)&Vb[rr * 64 + (((kh * 4 + quad) ^ sw) << 3)];
        o[dg] = __builtin_amdgcn_mfma_f32_16x16x32_bf16(vf, pf, o[dg], 0, 0, 0);
    }
}

// smem carve (u16 units): Ks[3] at 0/4096/8192, Vs[3] at 12288/16384/20480,
// P 8 waves x 2 tiles x 16*PST2 [24576,34816), l-exchange 128 f32 [34816,35072)
#define ATTN_SM_U16 35072
#define ATTN_SMEM_BYTES (ATTN_SM_U16 * 2)   // 70144

__global__ __launch_bounds__(512, 2) void attn_kernel(
    const u16* __restrict__ Q, const u16* __restrict__ K,
    const u16* __restrict__ Vt, u16* __restrict__ Y)
{
    extern __shared__ __align__(16) u16 asmem[];
    int t = threadIdx.x;
    int w = t >> 6, lane = t & 63;
    int m = lane & 15, quad = lane >> 4;
    int iq = w >> 1, kh = w & 1;         // q-slice 0..3, kv-half 0..1

    int bid = blockIdx.x;
    int head = bid & 31;                 // head%8 = bid%8 -> XCD affinity
    int g = bid >> 5;                    // 0..15
    int pr = (g < 8) ? g : 23 - g;       // co-resident pair (bid, bid+256) sums const
    int qbA = pr;                        // light q-block (chunks 0..qbA)
    int qbB = 31 - pr;                   // heavy q-block (chunks 0..qbB)
    int rbA = qbA * 64 + iq * 16;
    int rbB = qbB * 64 + iq * 16;

    const u16* qpA = Q + ((size_t)head * TT + rbA + m) * HDD + quad * 8;
    const u16* qpB = Q + ((size_t)head * TT + rbB + m) * HDD + quad * 8;
    bf16x8 qA0 = *(const bf16x8*)qpA;
    bf16x8 qA1 = *(const bf16x8*)(qpA + 32);
    bf16x8 qB0 = *(const bf16x8*)qpB;
    bf16x8 qB1 = *(const bf16x8*)(qpB + 32);

    // bf16 1.0 = 0x3F80 in every element (A-operand for the l row-sum MFMA)
    bf16x8 ones;
#pragma unroll
    for (int i = 0; i < 8; ++i) ones[i] = (short)0x3F80;

    const u16* kbase = K + (size_t)head * TT * HDD;   // [t][d]
    const u16* vbase = Vt + (size_t)head * HDD * TT;  // [d][t]
    u16* pbA = asmem + 24576 + (w * 2 + 0) * (16 * PST2);
    u16* pbB = asmem + 24576 + (w * 2 + 1) * (16 * PST2);

    // staging geometry: each of 8 waves stages 8 K-rows + 8 V-rows
    int lr = lane >> 3;
    int cg = (lane & 7) ^ lr;            // XOR swizzle on global col-group
    int r0 = w * 8 + lr;                 // 0..63
    int loff = (w * 64 + lane) * 8;      // u16 offset within one 4096-u16 buffer

    f32x4 zero = {0.f, 0.f, 0.f, 0.f};
    f32x4 oA[4], oB[4], laA = zero, laB = zero;
#pragma unroll
    for (int dg = 0; dg < 4; ++dg) { oA[dg] = zero; oB[dg] = zero; }
    int qcA = rbA + m, qcB = rbB + m;
    int sw = m & 7;

    // pointer-bump staging sources (advance once per prefetch)
    const u16* kst = kbase + (size_t)r0 * 64 + cg * 8;   // K rows: +64*HDD/chunk
    const u16* vst = vbase + (size_t)r0 * TT + cg * 8;   // V cols: +64/chunk

    // prologue: stage chunk 0 -> buf0, chunk 1 -> buf1 (4 loads in flight)
    async_copy16(kst, asmem + loff);
    async_copy16(vst, asmem + 12288 + loff);
    kst += 64 * HDD; vst += 64;
    async_copy16(kst, asmem + 4096 + loff);
    async_copy16(vst, asmem + 16384 + loff);
    kst += 64 * HDD; vst += 64;

// cross-tile P-pipelined chunk: qk_A -> pfA -> qk_B -> pv_A -> pfB -> pv_B
#define ATTN_CHUNK(KBUF, VBUF, IC) do {                                             \
    int kvb_ = ((IC) << 6) + kh * 32;                                               \
    bool hasA_ = (IC) <= qbA;                                                       \
    if ((IC) < qbA)                                                                 \
        tile_qk<false>(KBUF, pbA, qA0, qA1, m, quad, sw, kh, kvb_, qcA);            \
    else if ((IC) == qbA)                                                           \
        tile_qk<true >(KBUF, pbA, qA0, qA1, m, quad, sw, kh, kvb_, qcA);            \
    bf16x8 pfA_; if (hasA_) pfA_ = load_pf(pbA, m, quad);                           \
    if ((IC) < qbB)                                                                 \
        tile_qk<false>(KBUF, pbB, qB0, qB1, m, quad, sw, kh, kvb_, qcB);            \
    else                                                                            \
        tile_qk<true >(KBUF, pbB, qB0, qB1, m, quad, sw, kh, kvb_, qcB);            \
    if (hasA_) tile_pv(VBUF, pfA_, ones, m, quad, sw, kh, oA, laA);                 \
    bf16x8 pfB_ = load_pf(pbB, m, quad);                                            \
    tile_pv(VBUF, pfB_, ones, m, quad, sw, kh, oB, laB);                            \
  } while (0)

// one chunk body: counted-vmcnt wait (chunk IC's 2 loads are the oldest of 4
// outstanding when IC<qbB; only 2 outstanding at IC==qbB -> drain), raw
// barrier, prefetch chunk IC+2 into the rotation buffer, compute chunk IC.
// lgkmcnt(0) before the barrier = WAR fence for the prefetch overwrite.
#define ATTN_BODY(IC, KBUF, VBUF, PKBUF, PVBUF) do {                                \
    if ((IC) < qbB) asm volatile("s_waitcnt vmcnt(2) lgkmcnt(0)" ::: "memory");     \
    else            asm volatile("s_waitcnt vmcnt(0) lgkmcnt(0)" ::: "memory");     \
    __builtin_amdgcn_s_barrier();                                                   \
    asm volatile("" ::: "memory");                                                  \
    if ((IC) + 2 <= qbB) {                                                          \
        async_copy16(kst, (PKBUF) + loff);                                          \
        async_copy16(vst, (PVBUF) + loff);                                          \
        kst += 64 * HDD; vst += 64;                                                 \
    }                                                                               \
    ATTN_CHUNK(KBUF, VBUF, IC);                                                     \
  } while (0)

    int ic = 0;
    // triple-unrolled rotation: chunk c lives in buf c%3 (compile-time bases)
    while (ic + 2 <= qbB) {
        ATTN_BODY(ic,     asmem,        asmem + 12288, asmem + 8192, asmem + 20480);
        ATTN_BODY(ic + 1, asmem + 4096, asmem + 16384, asmem,        asmem + 12288);
        ATTN_BODY(ic + 2, asmem + 8192, asmem + 20480, asmem + 4096, asmem + 16384);
        ic += 3;
    }
    if (ic <= qbB) {           // tail chunk in buf0 (no prefetch: ic+2 > qbB)
        ATTN_BODY(ic, asmem, asmem + 12288, asmem + 8192, asmem + 20480);
        ++ic;
    }
    if (ic <= qbB) {           // tail chunk in buf1
        ATTN_BODY(ic, asmem + 4096, asmem + 16384, asmem, asmem + 12288);
        ++ic;
    }
#undef ATTN_BODY
#undef ATTN_CHUNK

    // l_q already fully reduced over this wave's kv-half (MFMA k-reduction):
    // every lane holds l for q=lane&15 in every lacc reg.
    float lA = laA[0];
    float lB = laB[0];

    // cross-kh combine: kh=1 writes O-partials + l, kh=0 merges & stores
    __syncthreads();
    f32x4* ob = (f32x4*)asmem;                // 32KB overlay on K/V buffers
    float* lb = (float*)&asmem[34816];        // 128 floats
    if (kh) {
        f32x4* dst = ob + (size_t)iq * 512 + lane;
#pragma unroll
        for (int dg = 0; dg < 4; ++dg) {
            dst[dg * 64] = oA[dg];
            dst[(4 + dg) * 64] = oB[dg];
        }
        if (quad == 0) {
            lb[(iq * 2 + 0) * 16 + m] = lA;
            lb[(iq * 2 + 1) * 16 + m] = lB;
        }
    }
    __syncthreads();
    if (!kh) {
        f32x4* src = ob + (size_t)iq * 512 + lane;
#pragma unroll
        for (int dg = 0; dg < 4; ++dg) {
            oA[dg] += src[dg * 64];
            oB[dg] += src[(4 + dg) * 64];
        }
        lA += lb[(iq * 2 + 0) * 16 + m];
        lB += lb[(iq * 2 + 1) * 16 + m];
        float invA = 1.0f / lA, invB = 1.0f / lB;

        int b = head >> 4, h = head & 15;
        size_t roA = ((size_t)(b * TT + rbA + m)) * CCH + h * HDD;
        size_t roB = ((size_t)(b * TT + rbB + m)) * CCH + h * HDD;
#pragma unroll
        for (int dg = 0; dg < 4; ++dg) {
            uint2 ov;
            ov.x = pk_bf16(oA[dg][0] * invA, oA[dg][1] * invA);
            ov.y = pk_bf16(oA[dg][2] * invA, oA[dg][3] * invA);
            *(uint2*)&Y[roA + dg * 16 + quad * 4] = ov;
            ov.x = pk_bf16(oB[dg][0] * invB, oB[dg][1] * invB);
            ov.y = pk_bf16(oB[dg][2] * invB, oB[dg][3] * invB);
            *(uint2*)&Y[roB + dg * 16 + quad * 4] = ov;
        }
    }
}

// ---------------- launch ----------------

extern "C" void kernel_launch(void* const* d_in, const int* in_sizes, int n_in,
                              void* d_out, int out_size, void* d_ws, size_t ws_size,
                              hipStream_t stream) {
    const float* x      = (const float*)d_in[0];
    const float* w_attn = (const float*)d_in[1];
    const float* w_proj = (const float*)d_in[2];
    float* out = (float*)d_out;

    char* ws = (char*)d_ws;
    u16* x_bf   = (u16*)ws; ws += (size_t)M_TOK * CCH * 2;         // 8 MB
    u16* wqkvT  = (u16*)ws; ws += (size_t)N_QKV * CCH * 2;         // 6 MB
    u16* wprojT = (u16*)ws; ws += (size_t)CCH * CCH * 2;           // 2 MB
    u16* qbuf   = (u16*)ws; ws += (size_t)BB * NHH * TT * HDD * 2; // 8 MB
    u16* kbuf   = (u16*)ws; ws += (size_t)BB * NHH * TT * HDD * 2; // 8 MB
    u16* vtb    = (u16*)ws; ws += (size_t)BB * NHH * HDD * TT * 2; // 8 MB
    u16* yb     = (u16*)ws; ws += (size_t)M_TOK * CCH * 2;         // 8 MB

    // one-time: allow big dynamic LDS for the pipelined kernels (host-side)
    static bool attr_done = false;
    if (!attr_done) {
        (void)hipFuncSetAttribute(reinterpret_cast<const void*>(qkv_gemm_kernel),
                                  hipFuncAttributeMaxDynamicSharedMemorySize,
                                  QKV_SMEM_BYTES);
        (void)hipFuncSetAttribute(reinterpret_cast<const void*>(proj_gemm_kernel),
                                  hipFuncAttributeMaxDynamicSharedMemorySize,
                                  PRJ_SMEM_BYTES);
        (void)hipFuncSetAttribute(reinterpret_cast<const void*>(attn_kernel),
                                  hipFuncAttributeMaxDynamicSharedMemorySize,
                                  ATTN_SMEM_BYTES);
        attr_done = true;
    }

    // softmax scale * log2(e), folded into Q columns of w_attn during transpose
    const float QSC = 0.125f * 1.44269504088896f;

    // 1. cast x -> bf16
    cast_bf16_kernel<<<dim3(M_TOK * CCH / 4 / 256), dim3(256), 0, stream>>>(x, x_bf, M_TOK * CCH / 4);
    // 2. transpose weights -> bf16 [N][K]
    transpose_bf16_kernel<<<dim3(N_QKV / 32, CCH / 32), dim3(32, 8), 0, stream>>>(
        w_attn, wqkvT, CCH, N_QKV, CCH, QSC);
    transpose_bf16_kernel<<<dim3(CCH / 32, CCH / 32), dim3(32, 8), 0, stream>>>(
        w_proj, wprojT, CCH, CCH, 0, 1.0f);
    // 3. QKV GEMM v2: 256 blocks (1/CU), 256x192 tiles, counted-vmcnt pipeline
    qkv_gemm_kernel<<<dim3(16, 16), dim3(512), QKV_SMEM_BYTES, stream>>>(
        x_bf, wqkvT, qbuf, kbuf, vtb);
    // 4. flash attention v18 (cross-tile P-roundtrip pipelining)
    attn_kernel<<<dim3(512), dim3(512), ATTN_SMEM_BYTES, stream>>>(qbuf, kbuf, vtb, yb);
    // 5. proj GEMM v2: 256 blocks (1/CU), 128x128 tiles, counted-vmcnt pipeline
    proj_gemm_kernel<<<dim3(8, 32), dim3(512), PRJ_SMEM_BYTES, stream>>>(
        yb, wprojT, out);
}

// Round 12
// 161.422 us; speedup vs baseline: 1.0615x; 1.0615x over previous
//
#include <hip/hip_runtime.h>
#include <hip/hip_bf16.h>

#define BB 2
#define TT 2048
#define CCH 1024
#define NHH 16
#define HDD 64
#define M_TOK (BB*TT)      // 4096
#define N_QKV (3*CCH)      // 3072

typedef __attribute__((ext_vector_type(8))) short bf16x8;
typedef __attribute__((ext_vector_type(4))) float f32x4;
typedef unsigned short u16;
typedef unsigned int u32;

__device__ __forceinline__ u16 f2bf(float f) {
    union { float f; u32 u; } v; v.f = f;
    u32 u = v.u;
    u32 r = (u + 0x7FFFu + ((u >> 16) & 1u)) >> 16;
    return (u16)r;
}

// pack hi16(a),hi16(b) -> u32 {b.hi<<16 | a.hi} with +0x8000 rounding
__device__ __forceinline__ u32 pk_bf16(float a, float b) {
    u32 ua = __float_as_uint(a) + 0x8000u;
    u32 ub = __float_as_uint(b) + 0x8000u;
    return __builtin_amdgcn_perm(ub, ua, 0x07060302u);
}

__device__ __forceinline__ void async_copy16(const void* g, void* l) {
    __builtin_amdgcn_global_load_lds((__attribute__((address_space(1))) void*)g,
                                     (__attribute__((address_space(3))) void*)l,
                                     16, 0, 0);
}

// ---------------- pre-pass kernels ----------------

__global__ __launch_bounds__(256) void cast_bf16_kernel(
    const float* __restrict__ src, u16* __restrict__ dst, int n4) {
    int i = blockIdx.x * 256 + threadIdx.x;
    if (i < n4) {
        float4 f = ((const float4*)src)[i];
        ushort4 o;
        o.x = f2bf(f.x); o.y = f2bf(f.y); o.z = f2bf(f.z); o.w = f2bf(f.w);
        ((ushort4*)dst)[i] = o;
    }
}

// src [R][Cn] fp32 -> dst [Cn][R] bf16; rows of dst with index < scale_rows get *= sc
__global__ __launch_bounds__(256) void transpose_bf16_kernel(
    const float* __restrict__ src, u16* __restrict__ dst, int R, int Cn,
    int scale_rows, float sc) {
    __shared__ float tile[32][33];
    int c0 = blockIdx.x * 32, r0 = blockIdx.y * 32;
    int tx = threadIdx.x, ty = threadIdx.y;
#pragma unroll
    for (int i = ty; i < 32; i += 8)
        tile[i][tx] = src[(size_t)(r0 + i) * Cn + c0 + tx];
    __syncthreads();
#pragma unroll
    for (int i = ty; i < 32; i += 8) {
        float v = tile[tx][i];
        if (c0 + i < scale_rows) v *= sc;
        dst[(size_t)(c0 + i) * R + r0 + tx] = f2bf(v);
    }
}

// ---------------- QKV GEMM v2: 256x192 tiles, counted-vmcnt pipeline (R7 WIN) ----------------

#define QKV_NK 16            // K / 64
#define QKV_AS_HALF 16384    // 256*64 u16
#define QKV_BS_HALF 12288    // 192*64 u16
#define QKV_SMEM_BYTES ((2*QKV_AS_HALF + 2*QKV_BS_HALF) * 2)   // 114688

__global__ __launch_bounds__(512, 1) void qkv_gemm_kernel(
    const u16* __restrict__ A, const u16* __restrict__ Bt,
    u16* __restrict__ Qo, u16* __restrict__ Ko, u16* __restrict__ Vto)
{
    extern __shared__ __align__(16) u16 smem[];
    u16* AsB = smem;                       // 2 x 256*64
    u16* BsB = smem + 2 * QKV_AS_HALF;     // 2 x 192*64
    int t = threadIdx.x;
    int lane = t & 63, w = t >> 6;
    int m0 = blockIdx.y * 256, n0 = blockIdx.x * 192;
    int mw = (w >> 1) * 64, nw = (w & 1) * 96;
    int mr = lane & 15, quad = lane >> 4, swm = mr & 7;

    f32x4 zero = {0.f, 0.f, 0.f, 0.f};
    f32x4 acc[4][6];
#pragma unroll
    for (int i = 0; i < 4; ++i)
#pragma unroll
        for (int j = 0; j < 6; ++j) acc[i][j] = zero;

    // staging geometry (verified pattern: 8 lanes/row, chunk c stored at c^(row&7))
    int lr = lane >> 3;
    int cswz = (lane & 7) ^ lr;
    const u16* gA[4]; int lAo[4];
#pragma unroll
    for (int p = 0; p < 4; ++p) {
        int grp = w * 4 + p;               // 32 groups x 8 rows = 256
        gA[p] = A + (size_t)(m0 + grp * 8 + lr) * CCH + cswz * 8;
        lAo[p] = (grp * 64 + lane) * 8;
    }
    const u16* gB[3]; int lBo[3];
#pragma unroll
    for (int p = 0; p < 3; ++p) {
        int grp = w * 3 + p;               // 24 groups x 8 rows = 192
        gB[p] = Bt + (size_t)(n0 + grp * 8 + lr) * CCH + cswz * 8;
        lBo[p] = (grp * 64 + lane) * 8;
    }

#define QKV_STAGE(K0, BUF) do {                                               \
    u16* dA_ = AsB + (BUF) * QKV_AS_HALF;                                     \
    u16* dB_ = BsB + (BUF) * QKV_BS_HALF;                                     \
    _Pragma("unroll") for (int p_ = 0; p_ < 4; ++p_)                          \
        async_copy16(gA[p_] + (K0), dA_ + lAo[p_]);                           \
    _Pragma("unroll") for (int p_ = 0; p_ < 3; ++p_)                          \
        async_copy16(gB[p_] + (K0), dB_ + lBo[p_]);                           \
  } while (0)

    // prologue: tiles 0 and 1 in flight (14 loads outstanding)
    QKV_STAGE(0, 0);
    QKV_STAGE(64, 1);

    for (int k = 0; k < QKV_NK; ++k) {
        int cur = k & 1;
        if (k == QKV_NK - 1) asm volatile("s_waitcnt vmcnt(0)" ::: "memory");
        else                 asm volatile("s_waitcnt vmcnt(7)" ::: "memory");
        __builtin_amdgcn_s_barrier();      // all waves: tile k fully staged
        asm volatile("" ::: "memory");
        const u16* Ac = AsB + cur * QKV_AS_HALF;
        const u16* Bc = BsB + cur * QKV_BS_HALF;
        bf16x8 a0[4], a1[4], b0[6], b1[6];
#pragma unroll
        for (int i = 0; i < 4; ++i) {
            int r = (mw + i * 16 + mr) * 64;
            a0[i] = *(const bf16x8*)&Ac[r + ((quad ^ swm) << 3)];
            a1[i] = *(const bf16x8*)&Ac[r + (((quad + 4) ^ swm) << 3)];
        }
#pragma unroll
        for (int j = 0; j < 6; ++j) {
            int r = (nw + j * 16 + mr) * 64;
            b0[j] = *(const bf16x8*)&Bc[r + ((quad ^ swm) << 3)];
            b1[j] = *(const bf16x8*)&Bc[r + (((quad + 4) ^ swm) << 3)];
        }
#pragma unroll
        for (int i = 0; i < 4; ++i)
#pragma unroll
            for (int j = 0; j < 6; ++j)
                acc[i][j] = __builtin_amdgcn_mfma_f32_16x16x32_bf16(b0[j], a0[i], acc[i][j], 0, 0, 0);
        asm volatile("s_waitcnt lgkmcnt(0)" ::: "memory");
        __builtin_amdgcn_sched_barrier(0);
        __builtin_amdgcn_s_barrier();      // all waves done reading buf cur
        asm volatile("" ::: "memory");
        if (k < QKV_NK - 2) QKV_STAGE((k + 2) * 64, cur);  // WAR-safe overwrite
#pragma unroll
        for (int i = 0; i < 4; ++i)
#pragma unroll
            for (int j = 0; j < 6; ++j)
                acc[i][j] = __builtin_amdgcn_mfma_f32_16x16x32_bf16(b1[j], a1[i], acc[i][j], 0, 0, 0);
    }
#undef QKV_STAGE

    // epilogue: C^T fragments; part decided per 16-col fragment (wave-uniform)
#pragma unroll
    for (int i = 0; i < 4; ++i)
#pragma unroll
        for (int j = 0; j < 6; ++j) {
            int tok = m0 + mw + i * 16 + mr;
            int cg0 = n0 + nw + j * 16 + quad * 4;
            int part = cg0 >> 10;
            int cc = cg0 & 1023;
            int h = cc >> 6, d0 = cc & 63;
            int b = tok >> 11, tt = tok & 2047;
            int bh = b * NHH + h;
            if (part < 2) {
                u16* dstp = part ? Ko : Qo;
                uint2 o;
                o.x = pk_bf16(acc[i][j][0], acc[i][j][1]);
                o.y = pk_bf16(acc[i][j][2], acc[i][j][3]);
                *(uint2*)&dstp[((size_t)bh * TT + tt) * HDD + d0] = o;
            } else {
#pragma unroll
                for (int r = 0; r < 4; ++r)
                    Vto[((size_t)bh * HDD + d0 + r) * TT + tt] = f2bf(acc[i][j][r]);
            }
        }
}

// ---------------- proj GEMM v2: 128x128 tiles, counted-vmcnt pipeline (R8 WIN) ----------------

#define PRJ_NK 16            // K / 64
#define PRJ_AS_HALF 8192     // 128*64 u16
#define PRJ_SMEM_BYTES (4 * PRJ_AS_HALF * 2)   // 65536

__global__ __launch_bounds__(512, 1) void proj_gemm_kernel(
    const u16* __restrict__ A, const u16* __restrict__ Bt, float* __restrict__ Cout)
{
    extern __shared__ __align__(16) u16 psmem[];
    u16* AsB = psmem;                      // 2 x 128*64
    u16* BsB = psmem + 2 * PRJ_AS_HALF;    // 2 x 128*64
    int t = threadIdx.x;
    int lane = t & 63, w = t >> 6;
    int m0 = blockIdx.y * 128, n0 = blockIdx.x * 128;
    int mw = (w >> 1) * 32, nw = (w & 1) * 64;
    int mr = lane & 15, quad = lane >> 4, swm = mr & 7;

    f32x4 zero = {0.f, 0.f, 0.f, 0.f};
    f32x4 acc[2][4];
#pragma unroll
    for (int i = 0; i < 2; ++i)
#pragma unroll
        for (int j = 0; j < 4; ++j) acc[i][j] = zero;

    int lr = lane >> 3;
    int cswz = (lane & 7) ^ lr;
    const u16* gA[2]; int lAo[2];
#pragma unroll
    for (int p = 0; p < 2; ++p) {
        int grp = w * 2 + p;               // 16 groups x 8 rows = 128
        gA[p] = A + (size_t)(m0 + grp * 8 + lr) * CCH + cswz * 8;
        lAo[p] = (grp * 64 + lane) * 8;
    }
    const u16* gB[2]; int lBo[2];
#pragma unroll
    for (int p = 0; p < 2; ++p) {
        int grp = w * 2 + p;               // 16 groups x 8 rows = 128
        gB[p] = Bt + (size_t)(n0 + grp * 8 + lr) * CCH + cswz * 8;
        lBo[p] = (grp * 64 + lane) * 8;
    }

#define PRJ_STAGE(K0, BUF) do {                                               \
    u16* dA_ = AsB + (BUF) * PRJ_AS_HALF;                                     \
    u16* dB_ = BsB + (BUF) * PRJ_AS_HALF;                                     \
    _Pragma("unroll") for (int p_ = 0; p_ < 2; ++p_)                          \
        async_copy16(gA[p_] + (K0), dA_ + lAo[p_]);                           \
    _Pragma("unroll") for (int p_ = 0; p_ < 2; ++p_)                          \
        async_copy16(gB[p_] + (K0), dB_ + lBo[p_]);                           \
  } while (0)

    PRJ_STAGE(0, 0);
    PRJ_STAGE(64, 1);

    for (int k = 0; k < PRJ_NK; ++k) {
        int cur = k & 1;
        if (k == PRJ_NK - 1) asm volatile("s_waitcnt vmcnt(0)" ::: "memory");
        else                 asm volatile("s_waitcnt vmcnt(4)" ::: "memory");
        __builtin_amdgcn_s_barrier();      // tile k fully staged
        asm volatile("" ::: "memory");
        const u16* Ac = AsB + cur * PRJ_AS_HALF;
        const u16* Bc = BsB + cur * PRJ_AS_HALF;
        bf16x8 a0[2], a1[2], b0[4], b1[4];
#pragma unroll
        for (int i = 0; i < 2; ++i) {
            int r = (mw + i * 16 + mr) * 64;
            a0[i] = *(const bf16x8*)&Ac[r + ((quad ^ swm) << 3)];
            a1[i] = *(const bf16x8*)&Ac[r + (((quad + 4) ^ swm) << 3)];
        }
#pragma unroll
        for (int j = 0; j < 4; ++j) {
            int r = (nw + j * 16 + mr) * 64;
            b0[j] = *(const bf16x8*)&Bc[r + ((quad ^ swm) << 3)];
            b1[j] = *(const bf16x8*)&Bc[r + (((quad + 4) ^ swm) << 3)];
        }
#pragma unroll
        for (int i = 0; i < 2; ++i)
#pragma unroll
            for (int j = 0; j < 4; ++j)
                acc[i][j] = __builtin_amdgcn_mfma_f32_16x16x32_bf16(b0[j], a0[i], acc[i][j], 0, 0, 0);
        asm volatile("s_waitcnt lgkmcnt(0)" ::: "memory");
        __builtin_amdgcn_sched_barrier(0);
        __builtin_amdgcn_s_barrier();      // all waves done reading buf cur
        asm volatile("" ::: "memory");
        if (k < PRJ_NK - 2) PRJ_STAGE((k + 2) * 64, cur);
#pragma unroll
        for (int i = 0; i < 2; ++i)
#pragma unroll
            for (int j = 0; j < 4; ++j)
                acc[i][j] = __builtin_amdgcn_mfma_f32_16x16x32_bf16(b1[j], a1[i], acc[i][j], 0, 0, 0);
    }
#undef PRJ_STAGE

    // epilogue: C^T fragments (tok on lane&15), float4 stores
#pragma unroll
    for (int i = 0; i < 2; ++i)
#pragma unroll
        for (int j = 0; j < 4; ++j) {
            int tok = m0 + mw + i * 16 + mr;
            int cg0 = n0 + nw + j * 16 + quad * 4;
            float4 v;
            v.x = acc[i][j][0]; v.y = acc[i][j][1];
            v.z = acc[i][j][2]; v.w = acc[i][j][3];
            *(float4*)&Cout[(size_t)tok * CCH + cg0] = v;
        }
}

// ---------------- flash attention v19: q-widened waves, shared fragments ----------------
// R11 diagnosis: attn is LDS-ISSUE-THROUGHPUT bound. v18 per wave-chunk:
// 18 b128 (8 kf + 8 vf + 2 pf, A/B each re-reading identical kf/vf) + 4 b64
// ~= 260cy of LDS pipe; x8 waves x49 chunk-steps/CU = 102k cy = 42.5us ~=
// measured 43.5. Explains all six nulls (VALU/vmcnt/reorder are off-pipe).
// v19: each block owns ONE 128-row q-block; wave = 32 q-rows (2x16 subtiles)
// x kv-half; kf/vf hoisted ONCE per chunk, shared across both subtiles:
// 10 b128 + 4 b64 per wave-chunk, and per-CU chunk-steps 49->34 (pairing:
// co-resident blocks get qb and 15-qb, sum 34 = const). LDS-pipe floor
// 45k cy = 18.6us. Mask iff ic >= 2*qb (proven: kv_max < qb*128 <= qcol
// for all earlier chunks). Staging/rotation/vmcnt/tile math verbatim.

#define PST2 40   // P row stride (u16): 16B-aligned rows

template<bool MASK>
__device__ __forceinline__ void tile_qk2(
    const bf16x8 (&kf)[2][2], u16* __restrict__ pb,
    bf16x8 qf0, bf16x8 qf1, int m, int quad,
    int kvb, int qcol)
{
    f32x4 zero = {0.f, 0.f, 0.f, 0.f};
#pragma unroll
    for (int kc = 0; kc < 2; ++kc) {
        // S^T: kv = kvb + kc*16 + quad*4 + r (rows), q = qcol (cols)
        f32x4 s  = __builtin_amdgcn_mfma_f32_16x16x32_bf16(kf[kc][0], qf0, zero, 0, 0, 0);
        f32x4 st = __builtin_amdgcn_mfma_f32_16x16x32_bf16(kf[kc][1], qf1, s, 0, 0, 0);
        float e0, e1, e2, e3;
#pragma unroll
        for (int r = 0; r < 4; ++r) {
            float v = st[r];
            if (MASK && (kvb + kc * 16 + quad * 4 + r > qcol)) v = -1e30f;
            float e = __builtin_amdgcn_exp2f(v);
            if (r == 0) e0 = e; else if (r == 1) e1 = e; else if (r == 2) e2 = e; else e3 = e;
        }
        uint2 pk; pk.x = pk_bf16(e0, e1); pk.y = pk_bf16(e2, e3);
        *(uint2*)&pb[m * PST2 + kc * 16 + quad * 4] = pk;
    }
}

__device__ __forceinline__ bf16x8 load_pf(const u16* __restrict__ pb, int m, int quad) {
    return *(const bf16x8*)&pb[m * PST2 + quad * 8];
}

__device__ __forceinline__ void tile_pv2(
    const bf16x8 (&vf)[4], bf16x8 pf, bf16x8 ones,
    f32x4 (&o)[4], f32x4& lacc)
{
    // l-row-sum rides the MFMA pipe (P.1)
    lacc = __builtin_amdgcn_mfma_f32_16x16x32_bf16(ones, pf, lacc, 0, 0, 0);
#pragma unroll
    for (int dg = 0; dg < 4; ++dg)
        o[dg] = __builtin_amdgcn_mfma_f32_16x16x32_bf16(vf[dg], pf, o[dg], 0, 0, 0);
}

// smem carve (u16 units): Ks[3] at 0/4096/8192, Vs[3] at 12288/16384/20480,
// P 8 waves x 2 subtiles x 16*PST2 [24576,34816), l-exchange 128 f32 [34816,35072)
#define ATTN_SM_U16 35072
#define ATTN_SMEM_BYTES (ATTN_SM_U16 * 2)   // 70144

__global__ __launch_bounds__(512, 2) void attn_kernel(
    const u16* __restrict__ Q, const u16* __restrict__ K,
    const u16* __restrict__ Vt, u16* __restrict__ Y)
{
    extern __shared__ __align__(16) u16 asmem[];
    int t = threadIdx.x;
    int w = t >> 6, lane = t & 63;
    int m = lane & 15, quad = lane >> 4;
    int iq = w >> 1, kh = w & 1;         // q-slice 0..3 (32 rows each), kv-half 0..1

    int bid = blockIdx.x;
    int head = bid & 31;                 // head%8 = bid%8 -> XCD affinity
    int g = bid >> 5;                    // 0..15
    int qb = (g < 8) ? g : 23 - g;       // q-block 0..15; co-resident pair sums 15
    int lim = 2 * qb + 1;                // last kv-chunk index (chunks of 64)
    int rb = qb * 128 + iq * 32;         // wave's first q-row

    const u16* qp0 = Q + ((size_t)head * TT + rb + m) * HDD + quad * 8;
    const u16* qp1 = Q + ((size_t)head * TT + rb + 16 + m) * HDD + quad * 8;
    bf16x8 q00 = *(const bf16x8*)qp0;
    bf16x8 q01 = *(const bf16x8*)(qp0 + 32);
    bf16x8 q10 = *(const bf16x8*)qp1;
    bf16x8 q11 = *(const bf16x8*)(qp1 + 32);

    // bf16 1.0 = 0x3F80 in every element (A-operand for the l row-sum MFMA)
    bf16x8 ones;
#pragma unroll
    for (int i = 0; i < 8; ++i) ones[i] = (short)0x3F80;

    const u16* kbase = K + (size_t)head * TT * HDD;   // [t][d]
    const u16* vbase = Vt + (size_t)head * HDD * TT;  // [d][t]
    u16* pb0 = asmem + 24576 + (w * 2 + 0) * (16 * PST2);
    u16* pb1 = asmem + 24576 + (w * 2 + 1) * (16 * PST2);

    // staging geometry: each of 8 waves stages 8 K-rows + 8 V-rows
    int lr = lane >> 3;
    int cg = (lane & 7) ^ lr;            // XOR swizzle on global col-group
    int r0 = w * 8 + lr;                 // 0..63
    int loff = (w * 64 + lane) * 8;      // u16 offset within one 4096-u16 buffer

    f32x4 zero = {0.f, 0.f, 0.f, 0.f};
    f32x4 o0[4], o1[4], la0 = zero, la1 = zero;
#pragma unroll
    for (int dg = 0; dg < 4; ++dg) { o0[dg] = zero; o1[dg] = zero; }
    int qc0 = rb + m, qc1 = rb + 16 + m;
    int sw = m & 7;

    // pointer-bump staging sources (advance once per prefetch)
    const u16* kst = kbase + (size_t)r0 * 64 + cg * 8;   // K rows: +64*HDD/chunk
    const u16* vst = vbase + (size_t)r0 * TT + cg * 8;   // V cols: +64/chunk

    // prologue: stage chunk 0 -> buf0, chunk 1 -> buf1 (4 loads in flight)
    async_copy16(kst, asmem + loff);
    async_copy16(vst, asmem + 12288 + loff);
    kst += 64 * HDD; vst += 64;
    async_copy16(kst, asmem + 4096 + loff);
    async_copy16(vst, asmem + 16384 + loff);
    kst += 64 * HDD; vst += 64;

// chunk compute: hoist kf/vf once, share across both q-subtiles.
// order: qk(s0) -> pf0 -> qk(s1) -> pv(s0) -> pf1 -> pv(s1)  (P-roundtrip
// latency hidden under the other subtile's MFMA+exp issue)
#define ATTN_CHUNK(KBUF, VBUF, IC) do {                                             \
    int kvb_ = ((IC) << 6) + kh * 32;                                               \
    bool msk_ = (IC) >= 2 * qb;                                                     \
    bf16x8 kf_[2][2], vf_[4];                                                       \
    _Pragma("unroll") for (int kc_ = 0; kc_ < 2; ++kc_) {                           \
        int rr_ = kh * 32 + kc_ * 16 + m;                                           \
        kf_[kc_][0] = *(const bf16x8*)&(KBUF)[rr_ * 64 + ((quad ^ sw) << 3)];       \
        kf_[kc_][1] = *(const bf16x8*)&(KBUF)[rr_ * 64 + (((quad + 4) ^ sw) << 3)]; \
    }                                                                               \
    _Pragma("unroll") for (int dg_ = 0; dg_ < 4; ++dg_) {                           \
        int rr_ = dg_ * 16 + m;                                                     \
        vf_[dg_] = *(const bf16x8*)&(VBUF)[rr_ * 64 + (((kh * 4 + quad) ^ sw) << 3)]; \
    }                                                                               \
    if (msk_) tile_qk2<true >(kf_, pb0, q00, q01, m, quad, kvb_, qc0);              \
    else      tile_qk2<false>(kf_, pb0, q00, q01, m, quad, kvb_, qc0);              \
    bf16x8 pf0_ = load_pf(pb0, m, quad);                                            \
    if (msk_) tile_qk2<true >(kf_, pb1, q10, q11, m, quad, kvb_, qc1);              \
    else      tile_qk2<false>(kf_, pb1, q10, q11, m, quad, kvb_, qc1);              \
    tile_pv2(vf_, pf0_, ones, o0, la0);                                             \
    bf16x8 pf1_ = load_pf(pb1, m, quad);                                            \
    tile_pv2(vf_, pf1_, ones, o1, la1);                                             \
  } while (0)

// one chunk body: counted-vmcnt wait (chunk IC's 2 loads are the oldest of 4
// outstanding when IC<lim; only 2 outstanding at IC==lim -> drain), raw
// barrier, prefetch chunk IC+2 into the rotation buffer, compute chunk IC.
// lgkmcnt(0) before the barrier = WAR fence for the prefetch overwrite.
#define ATTN_BODY(IC, KBUF, VBUF, PKBUF, PVBUF) do {                                \
    if ((IC) < lim) asm volatile("s_waitcnt vmcnt(2) lgkmcnt(0)" ::: "memory");     \
    else            asm volatile("s_waitcnt vmcnt(0) lgkmcnt(0)" ::: "memory");     \
    __builtin_amdgcn_s_barrier();                                                   \
    asm volatile("" ::: "memory");                                                  \
    if ((IC) + 2 <= lim) {                                                          \
        async_copy16(kst, (PKBUF) + loff);                                          \
        async_copy16(vst, (PVBUF) + loff);                                          \
        kst += 64 * HDD; vst += 64;                                                 \
    }                                                                               \
    ATTN_CHUNK(KBUF, VBUF, IC);                                                     \
  } while (0)

    int ic = 0;
    // triple-unrolled rotation: chunk c lives in buf c%3 (compile-time bases)
    while (ic + 2 <= lim) {
        ATTN_BODY(ic,     asmem,        asmem + 12288, asmem + 8192, asmem + 20480);
        ATTN_BODY(ic + 1, asmem + 4096, asmem + 16384, asmem,        asmem + 12288);
        ATTN_BODY(ic + 2, asmem + 8192, asmem + 20480, asmem + 4096, asmem + 16384);
        ic += 3;
    }
    if (ic <= lim) {           // tail chunk in buf0 (no prefetch: ic+2 > lim)
        ATTN_BODY(ic, asmem, asmem + 12288, asmem + 8192, asmem + 20480);
        ++ic;
    }
    if (ic <= lim) {           // tail chunk in buf1
        ATTN_BODY(ic, asmem + 4096, asmem + 16384, asmem, asmem + 12288);
        ++ic;
    }
#undef ATTN_BODY
#undef ATTN_CHUNK

    // l fully reduced over this wave's kv-half (MFMA k-reduction):
    // every lane holds l for q=lane&15 in every lacc reg.
    float l0 = la0[0];
    float l1 = la1[0];

    // cross-kh combine: kh=1 writes O-partials + l, kh=0 merges & stores
    __syncthreads();
    f32x4* ob = (f32x4*)asmem;                // 32KB overlay on K/V buffers
    float* lb = (float*)&asmem[34816];        // 128 floats
    if (kh) {
        f32x4* dst = ob + (size_t)iq * 512 + lane;
#pragma unroll
        for (int dg = 0; dg < 4; ++dg) {
            dst[dg * 64] = o0[dg];
            dst[(4 + dg) * 64] = o1[dg];
        }
        if (quad == 0) {
            lb[(iq * 2 + 0) * 16 + m] = l0;
            lb[(iq * 2 + 1) * 16 + m] = l1;
        }
    }
    __syncthreads();
    if (!kh) {
        f32x4* src = ob + (size_t)iq * 512 + lane;
#pragma unroll
        for (int dg = 0; dg < 4; ++dg) {
            o0[dg] += src[dg * 64];
            o1[dg] += src[(4 + dg) * 64];
        }
        l0 += lb[(iq * 2 + 0) * 16 + m];
        l1 += lb[(iq * 2 + 1) * 16 + m];
        float inv0 = 1.0f / l0, inv1 = 1.0f / l1;

        int b = head >> 4, h = head & 15;
        size_t ro0 = ((size_t)(b * TT + rb + m)) * CCH + h * HDD;
        size_t ro1 = ((size_t)(b * TT + rb + 16 + m)) * CCH + h * HDD;
#pragma unroll
        for (int dg = 0; dg < 4; ++dg) {
            uint2 ov;
            ov.x = pk_bf16(o0[dg][0] * inv0, o0[dg][1] * inv0);
            ov.y = pk_bf16(o0[dg][2] * inv0, o0[dg][3] * inv0);
            *(uint2*)&Y[ro0 + dg * 16 + quad * 4] = ov;
            ov.x = pk_bf16(o1[dg][0] * inv1, o1[dg][1] * inv1);
            ov.y = pk_bf16(o1[dg][2] * inv1, o1[dg][3] * inv1);
            *(uint2*)&Y[ro1 + dg * 16 + quad * 4] = ov;
        }
    }
}

// ---------------- launch ----------------

extern "C" void kernel_launch(void* const* d_in, const int* in_sizes, int n_in,
                              void* d_out, int out_size, void* d_ws, size_t ws_size,
                              hipStream_t stream) {
    const float* x      = (const float*)d_in[0];
    const float* w_attn = (const float*)d_in[1];
    const float* w_proj = (const float*)d_in[2];
    float* out = (float*)d_out;

    char* ws = (char*)d_ws;
    u16* x_bf   = (u16*)ws; ws += (size_t)M_TOK * CCH * 2;         // 8 MB
    u16* wqkvT  = (u16*)ws; ws += (size_t)N_QKV * CCH * 2;         // 6 MB
    u16* wprojT = (u16*)ws; ws += (size_t)CCH * CCH * 2;           // 2 MB
    u16* qbuf   = (u16*)ws; ws += (size_t)BB * NHH * TT * HDD * 2; // 8 MB
    u16* kbuf   = (u16*)ws; ws += (size_t)BB * NHH * TT * HDD * 2; // 8 MB
    u16* vtb    = (u16*)ws; ws += (size_t)BB * NHH * HDD * TT * 2; // 8 MB
    u16* yb     = (u16*)ws; ws += (size_t)M_TOK * CCH * 2;         // 8 MB

    // one-time: allow big dynamic LDS for the pipelined kernels (host-side)
    static bool attr_done = false;
    if (!attr_done) {
        (void)hipFuncSetAttribute(reinterpret_cast<const void*>(qkv_gemm_kernel),
                                  hipFuncAttributeMaxDynamicSharedMemorySize,
                                  QKV_SMEM_BYTES);
        (void)hipFuncSetAttribute(reinterpret_cast<const void*>(proj_gemm_kernel),
                                  hipFuncAttributeMaxDynamicSharedMemorySize,
                                  PRJ_SMEM_BYTES);
        (void)hipFuncSetAttribute(reinterpret_cast<const void*>(attn_kernel),
                                  hipFuncAttributeMaxDynamicSharedMemorySize,
                                  ATTN_SMEM_BYTES);
        attr_done = true;
    }

    // softmax scale * log2(e), folded into Q columns of w_attn during transpose
    const float QSC = 0.125f * 1.44269504088896f;

    // 1. cast x -> bf16
    cast_bf16_kernel<<<dim3(M_TOK * CCH / 4 / 256), dim3(256), 0, stream>>>(x, x_bf, M_TOK * CCH / 4);
    // 2. transpose weights -> bf16 [N][K]
    transpose_bf16_kernel<<<dim3(N_QKV / 32, CCH / 32), dim3(32, 8), 0, stream>>>(
        w_attn, wqkvT, CCH, N_QKV, CCH, QSC);
    transpose_bf16_kernel<<<dim3(CCH / 32, CCH / 32), dim3(32, 8), 0, stream>>>(
        w_proj, wprojT, CCH, CCH, 0, 1.0f);
    // 3. QKV GEMM v2: 256 blocks (1/CU), 256x192 tiles, counted-vmcnt pipeline
    qkv_gemm_kernel<<<dim3(16, 16), dim3(512), QKV_SMEM_BYTES, stream>>>(
        x_bf, wqkvT, qbuf, kbuf, vtb);
    // 4. flash attention v19 (q-widened waves, shared K/V fragments)
    attn_kernel<<<dim3(512), dim3(512), ATTN_SMEM_BYTES, stream>>>(qbuf, kbuf, vtb, yb);
    // 5. proj GEMM v2: 256 blocks (1/CU), 128x128 tiles, counted-vmcnt pipeline
    proj_gemm_kernel<<<dim3(8, 32), dim3(512), PRJ_SMEM_BYTES, stream>>>(
        yb, wprojT, out);
}

// Round 13
// 158.188 us; speedup vs baseline: 1.0832x; 1.0204x over previous
//
#include <hip/hip_runtime.h>
#include <hip/hip_bf16.h>

#define BB 2
#define TT 2048
#define CCH 1024
#define NHH 16
#define HDD 64
#define M_TOK (BB*TT)      // 4096
#define N_QKV (3*CCH)      // 3072

typedef __attribute__((ext_vector_type(8))) short bf16x8;
typedef __attribute__((ext_vector_type(4))) float f32x4;
typedef unsigned short u16;
typedef unsigned int u32;

__device__ __forceinline__ u16 f2bf(float f) {
    union { float f; u32 u; } v; v.f = f;
    u32 u = v.u;
    u32 r = (u + 0x7FFFu + ((u >> 16) & 1u)) >> 16;
    return (u16)r;
}

// pack hi16(a),hi16(b) -> u32 {b.hi<<16 | a.hi} with +0x8000 rounding
__device__ __forceinline__ u32 pk_bf16(float a, float b) {
    u32 ua = __float_as_uint(a) + 0x8000u;
    u32 ub = __float_as_uint(b) + 0x8000u;
    return __builtin_amdgcn_perm(ub, ua, 0x07060302u);
}

__device__ __forceinline__ void async_copy16(const void* g, void* l) {
    __builtin_amdgcn_global_load_lds((__attribute__((address_space(1))) void*)g,
                                     (__attribute__((address_space(3))) void*)l,
                                     16, 0, 0);
}

// ---------------- merged pre-pass: cast + both weight transposes ----------------
// R13: one dispatch instead of three (saves 2 launch/gap overheads).
// blocks [0,4096): cast x -> bf16 (4 elem/thread)
// blocks [4096,7168): transpose w_attn -> wqkvT [N][K], Q-cols scaled by QSC
// blocks [7168,8192): transpose w_proj -> wprojT [N][K]

__global__ __launch_bounds__(256) void prepass_kernel(
    const float* __restrict__ x, const float* __restrict__ w_attn,
    const float* __restrict__ w_proj, u16* __restrict__ x_bf,
    u16* __restrict__ wqkvT, u16* __restrict__ wprojT)
{
    int bid = blockIdx.x;
    int t = threadIdx.x;
    if (bid < 4096) {                       // cast path (block-uniform branch)
        int i = bid * 256 + t;
        float4 f = ((const float4*)x)[i];
        ushort4 o;
        o.x = f2bf(f.x); o.y = f2bf(f.y); o.z = f2bf(f.z); o.w = f2bf(f.w);
        ((ushort4*)x_bf)[i] = o;
        return;
    }
    __shared__ float tile[32][33];
    const float* src; u16* dst; int Cn, scale_rows; float sc;
    int c0, r0;
    if (bid < 4096 + 3072) {                // w_attn transpose (grid was 96x32)
        int b = bid - 4096;
        src = w_attn; dst = wqkvT; Cn = N_QKV; scale_rows = CCH;
        sc = 0.125f * 1.44269504088896f;    // softmax scale * log2(e), Q cols
        c0 = (b % 96) * 32; r0 = (b / 96) * 32;
    } else {                                // w_proj transpose (grid was 32x32)
        int b = bid - 7168;
        src = w_proj; dst = wprojT; Cn = CCH; scale_rows = 0; sc = 1.0f;
        c0 = (b & 31) * 32; r0 = (b >> 5) * 32;
    }
    int tx = t & 31, ty = t >> 5;           // flattened (32,8)
#pragma unroll
    for (int i = ty; i < 32; i += 8)
        tile[i][tx] = src[(size_t)(r0 + i) * Cn + c0 + tx];
    __syncthreads();
#pragma unroll
    for (int i = ty; i < 32; i += 8) {
        float v = tile[tx][i];
        if (c0 + i < scale_rows) v *= sc;
        dst[(size_t)(c0 + i) * CCH + r0 + tx] = f2bf(v);
    }
}

// ---------------- QKV GEMM v2: 256x192 tiles, counted-vmcnt pipeline (R7 WIN) ----------------

#define QKV_NK 16            // K / 64
#define QKV_AS_HALF 16384    // 256*64 u16
#define QKV_BS_HALF 12288    // 192*64 u16
#define QKV_SMEM_BYTES ((2*QKV_AS_HALF + 2*QKV_BS_HALF) * 2)   // 114688

__global__ __launch_bounds__(512, 1) void qkv_gemm_kernel(
    const u16* __restrict__ A, const u16* __restrict__ Bt,
    u16* __restrict__ Qo, u16* __restrict__ Ko, u16* __restrict__ Vto)
{
    extern __shared__ __align__(16) u16 smem[];
    u16* AsB = smem;                       // 2 x 256*64
    u16* BsB = smem + 2 * QKV_AS_HALF;     // 2 x 192*64
    int t = threadIdx.x;
    int lane = t & 63, w = t >> 6;
    int m0 = blockIdx.y * 256, n0 = blockIdx.x * 192;
    int mw = (w >> 1) * 64, nw = (w & 1) * 96;
    int mr = lane & 15, quad = lane >> 4, swm = mr & 7;

    f32x4 zero = {0.f, 0.f, 0.f, 0.f};
    f32x4 acc[4][6];
#pragma unroll
    for (int i = 0; i < 4; ++i)
#pragma unroll
        for (int j = 0; j < 6; ++j) acc[i][j] = zero;

    // staging geometry (verified pattern: 8 lanes/row, chunk c stored at c^(row&7))
    int lr = lane >> 3;
    int cswz = (lane & 7) ^ lr;
    const u16* gA[4]; int lAo[4];
#pragma unroll
    for (int p = 0; p < 4; ++p) {
        int grp = w * 4 + p;               // 32 groups x 8 rows = 256
        gA[p] = A + (size_t)(m0 + grp * 8 + lr) * CCH + cswz * 8;
        lAo[p] = (grp * 64 + lane) * 8;
    }
    const u16* gB[3]; int lBo[3];
#pragma unroll
    for (int p = 0; p < 3; ++p) {
        int grp = w * 3 + p;               // 24 groups x 8 rows = 192
        gB[p] = Bt + (size_t)(n0 + grp * 8 + lr) * CCH + cswz * 8;
        lBo[p] = (grp * 64 + lane) * 8;
    }

#define QKV_STAGE(K0, BUF) do {                                               \
    u16* dA_ = AsB + (BUF) * QKV_AS_HALF;                                     \
    u16* dB_ = BsB + (BUF) * QKV_BS_HALF;                                     \
    _Pragma("unroll") for (int p_ = 0; p_ < 4; ++p_)                          \
        async_copy16(gA[p_] + (K0), dA_ + lAo[p_]);                           \
    _Pragma("unroll") for (int p_ = 0; p_ < 3; ++p_)                          \
        async_copy16(gB[p_] + (K0), dB_ + lBo[p_]);                           \
  } while (0)

    // prologue: tiles 0 and 1 in flight (14 loads outstanding)
    QKV_STAGE(0, 0);
    QKV_STAGE(64, 1);

    for (int k = 0; k < QKV_NK; ++k) {
        int cur = k & 1;
        if (k == QKV_NK - 1) asm volatile("s_waitcnt vmcnt(0)" ::: "memory");
        else                 asm volatile("s_waitcnt vmcnt(7)" ::: "memory");
        __builtin_amdgcn_s_barrier();      // all waves: tile k fully staged
        asm volatile("" ::: "memory");
        const u16* Ac = AsB + cur * QKV_AS_HALF;
        const u16* Bc = BsB + cur * QKV_BS_HALF;
        bf16x8 a0[4], a1[4], b0[6], b1[6];
#pragma unroll
        for (int i = 0; i < 4; ++i) {
            int r = (mw + i * 16 + mr) * 64;
            a0[i] = *(const bf16x8*)&Ac[r + ((quad ^ swm) << 3)];
            a1[i] = *(const bf16x8*)&Ac[r + (((quad + 4) ^ swm) << 3)];
        }
#pragma unroll
        for (int j = 0; j < 6; ++j) {
            int r = (nw + j * 16 + mr) * 64;
            b0[j] = *(const bf16x8*)&Bc[r + ((quad ^ swm) << 3)];
            b1[j] = *(const bf16x8*)&Bc[r + (((quad + 4) ^ swm) << 3)];
        }
#pragma unroll
        for (int i = 0; i < 4; ++i)
#pragma unroll
            for (int j = 0; j < 6; ++j)
                acc[i][j] = __builtin_amdgcn_mfma_f32_16x16x32_bf16(b0[j], a0[i], acc[i][j], 0, 0, 0);
        asm volatile("s_waitcnt lgkmcnt(0)" ::: "memory");
        __builtin_amdgcn_sched_barrier(0);
        __builtin_amdgcn_s_barrier();      // all waves done reading buf cur
        asm volatile("" ::: "memory");
        if (k < QKV_NK - 2) QKV_STAGE((k + 2) * 64, cur);  // WAR-safe overwrite
#pragma unroll
        for (int i = 0; i < 4; ++i)
#pragma unroll
            for (int j = 0; j < 6; ++j)
                acc[i][j] = __builtin_amdgcn_mfma_f32_16x16x32_bf16(b1[j], a1[i], acc[i][j], 0, 0, 0);
    }
#undef QKV_STAGE

    // epilogue: C^T fragments; part decided per 16-col fragment (wave-uniform)
#pragma unroll
    for (int i = 0; i < 4; ++i)
#pragma unroll
        for (int j = 0; j < 6; ++j) {
            int tok = m0 + mw + i * 16 + mr;
            int cg0 = n0 + nw + j * 16 + quad * 4;
            int part = cg0 >> 10;
            int cc = cg0 & 1023;
            int h = cc >> 6, d0 = cc & 63;
            int b = tok >> 11, tt = tok & 2047;
            int bh = b * NHH + h;
            if (part < 2) {
                u16* dstp = part ? Ko : Qo;
                uint2 o;
                o.x = pk_bf16(acc[i][j][0], acc[i][j][1]);
                o.y = pk_bf16(acc[i][j][2], acc[i][j][3]);
                *(uint2*)&dstp[((size_t)bh * TT + tt) * HDD + d0] = o;
            } else {
#pragma unroll
                for (int r = 0; r < 4; ++r)
                    Vto[((size_t)bh * HDD + d0 + r) * TT + tt] = f2bf(acc[i][j][r]);
            }
        }
}

// ---------------- proj GEMM v2: 128x128 tiles, counted-vmcnt pipeline (R8 WIN) ----------------

#define PRJ_NK 16            // K / 64
#define PRJ_AS_HALF 8192     // 128*64 u16
#define PRJ_SMEM_BYTES (4 * PRJ_AS_HALF * 2)   // 65536

__global__ __launch_bounds__(512, 1) void proj_gemm_kernel(
    const u16* __restrict__ A, const u16* __restrict__ Bt, float* __restrict__ Cout)
{
    extern __shared__ __align__(16) u16 psmem[];
    u16* AsB = psmem;                      // 2 x 128*64
    u16* BsB = psmem + 2 * PRJ_AS_HALF;    // 2 x 128*64
    int t = threadIdx.x;
    int lane = t & 63, w = t >> 6;
    int m0 = blockIdx.y * 128, n0 = blockIdx.x * 128;
    int mw = (w >> 1) * 32, nw = (w & 1) * 64;
    int mr = lane & 15, quad = lane >> 4, swm = mr & 7;

    f32x4 zero = {0.f, 0.f, 0.f, 0.f};
    f32x4 acc[2][4];
#pragma unroll
    for (int i = 0; i < 2; ++i)
#pragma unroll
        for (int j = 0; j < 4; ++j) acc[i][j] = zero;

    int lr = lane >> 3;
    int cswz = (lane & 7) ^ lr;
    const u16* gA[2]; int lAo[2];
#pragma unroll
    for (int p = 0; p < 2; ++p) {
        int grp = w * 2 + p;               // 16 groups x 8 rows = 128
        gA[p] = A + (size_t)(m0 + grp * 8 + lr) * CCH + cswz * 8;
        lAo[p] = (grp * 64 + lane) * 8;
    }
    const u16* gB[2]; int lBo[2];
#pragma unroll
    for (int p = 0; p < 2; ++p) {
        int grp = w * 2 + p;               // 16 groups x 8 rows = 128
        gB[p] = Bt + (size_t)(n0 + grp * 8 + lr) * CCH + cswz * 8;
        lBo[p] = (grp * 64 + lane) * 8;
    }

#define PRJ_STAGE(K0, BUF) do {                                               \
    u16* dA_ = AsB + (BUF) * PRJ_AS_HALF;                                     \
    u16* dB_ = BsB + (BUF) * PRJ_AS_HALF;                                     \
    _Pragma("unroll") for (int p_ = 0; p_ < 2; ++p_)                          \
        async_copy16(gA[p_] + (K0), dA_ + lAo[p_]);                           \
    _Pragma("unroll") for (int p_ = 0; p_ < 2; ++p_)                          \
        async_copy16(gB[p_] + (K0), dB_ + lBo[p_]);                           \
  } while (0)

    PRJ_STAGE(0, 0);
    PRJ_STAGE(64, 1);

    for (int k = 0; k < PRJ_NK; ++k) {
        int cur = k & 1;
        if (k == PRJ_NK - 1) asm volatile("s_waitcnt vmcnt(0)" ::: "memory");
        else                 asm volatile("s_waitcnt vmcnt(4)" ::: "memory");
        __builtin_amdgcn_s_barrier();      // tile k fully staged
        asm volatile("" ::: "memory");
        const u16* Ac = AsB + cur * PRJ_AS_HALF;
        const u16* Bc = BsB + cur * PRJ_AS_HALF;
        bf16x8 a0[2], a1[2], b0[4], b1[4];
#pragma unroll
        for (int i = 0; i < 2; ++i) {
            int r = (mw + i * 16 + mr) * 64;
            a0[i] = *(const bf16x8*)&Ac[r + ((quad ^ swm) << 3)];
            a1[i] = *(const bf16x8*)&Ac[r + (((quad + 4) ^ swm) << 3)];
        }
#pragma unroll
        for (int j = 0; j < 4; ++j) {
            int r = (nw + j * 16 + mr) * 64;
            b0[j] = *(const bf16x8*)&Bc[r + ((quad ^ swm) << 3)];
            b1[j] = *(const bf16x8*)&Bc[r + (((quad + 4) ^ swm) << 3)];
        }
#pragma unroll
        for (int i = 0; i < 2; ++i)
#pragma unroll
            for (int j = 0; j < 4; ++j)
                acc[i][j] = __builtin_amdgcn_mfma_f32_16x16x32_bf16(b0[j], a0[i], acc[i][j], 0, 0, 0);
        asm volatile("s_waitcnt lgkmcnt(0)" ::: "memory");
        __builtin_amdgcn_sched_barrier(0);
        __builtin_amdgcn_s_barrier();      // all waves done reading buf cur
        asm volatile("" ::: "memory");
        if (k < PRJ_NK - 2) PRJ_STAGE((k + 2) * 64, cur);
#pragma unroll
        for (int i = 0; i < 2; ++i)
#pragma unroll
            for (int j = 0; j < 4; ++j)
                acc[i][j] = __builtin_amdgcn_mfma_f32_16x16x32_bf16(b1[j], a1[i], acc[i][j], 0, 0, 0);
    }
#undef PRJ_STAGE

    // epilogue: C^T fragments (tok on lane&15), float4 stores
#pragma unroll
    for (int i = 0; i < 2; ++i)
#pragma unroll
        for (int j = 0; j < 4; ++j) {
            int tok = m0 + mw + i * 16 + mr;
            int cg0 = n0 + nw + j * 16 + quad * 4;
            float4 v;
            v.x = acc[i][j][0]; v.y = acc[i][j][1];
            v.z = acc[i][j][2]; v.w = acc[i][j][3];
            *(float4*)&Cout[(size_t)tok * CCH + cg0] = v;
        }
}

// ---------------- flash attention v20: v19 + T5 setprio ----------------
// v19 (q-widened waves, shared K/V fragments) was the best structure (best
// total 161.4). v20 adds only T5: s_setprio(1) around the per-chunk compute
// cluster. Mechanism (guide m191): 2 independent blocks/CU at different
// phases -> the CU scheduler favors compute-phase waves over the other
// block's staging waves. Attn-verified +4-7%; zero correctness risk.

#define PST2 40   // P row stride (u16): 16B-aligned rows

template<bool MASK>
__device__ __forceinline__ void tile_qk2(
    const bf16x8 (&kf)[2][2], u16* __restrict__ pb,
    bf16x8 qf0, bf16x8 qf1, int m, int quad,
    int kvb, int qcol)
{
    f32x4 zero = {0.f, 0.f, 0.f, 0.f};
#pragma unroll
    for (int kc = 0; kc < 2; ++kc) {
        // S^T: kv = kvb + kc*16 + quad*4 + r (rows), q = qcol (cols)
        f32x4 s  = __builtin_amdgcn_mfma_f32_16x16x32_bf16(kf[kc][0], qf0, zero, 0, 0, 0);
        f32x4 st = __builtin_amdgcn_mfma_f32_16x16x32_bf16(kf[kc][1], qf1, s, 0, 0, 0);
        float e0, e1, e2, e3;
#pragma unroll
        for (int r = 0; r < 4; ++r) {
            float v = st[r];
            if (MASK && (kvb + kc * 16 + quad * 4 + r > qcol)) v = -1e30f;
            float e = __builtin_amdgcn_exp2f(v);
            if (r == 0) e0 = e; else if (r == 1) e1 = e; else if (r == 2) e2 = e; else e3 = e;
        }
        uint2 pk; pk.x = pk_bf16(e0, e1); pk.y = pk_bf16(e2, e3);
        *(uint2*)&pb[m * PST2 + kc * 16 + quad * 4] = pk;
    }
}

__device__ __forceinline__ bf16x8 load_pf(const u16* __restrict__ pb, int m, int quad) {
    return *(const bf16x8*)&pb[m * PST2 + quad * 8];
}

__device__ __forceinline__ void tile_pv2(
    const bf16x8 (&vf)[4], bf16x8 pf, bf16x8 ones,
    f32x4 (&o)[4], f32x4& lacc)
{
    // l-row-sum rides the MFMA pipe (P.1)
    lacc = __builtin_amdgcn_mfma_f32_16x16x32_bf16(ones, pf, lacc, 0, 0, 0);
#pragma unroll
    for (int dg = 0; dg < 4; ++dg)
        o[dg] = __builtin_amdgcn_mfma_f32_16x16x32_bf16(vf[dg], pf, o[dg], 0, 0, 0);
}

// smem carve (u16 units): Ks[3] at 0/4096/8192, Vs[3] at 12288/16384/20480,
// P 8 waves x 2 subtiles x 16*PST2 [24576,34816), l-exchange 128 f32 [34816,35072)
#define ATTN_SM_U16 35072
#define ATTN_SMEM_BYTES (ATTN_SM_U16 * 2)   // 70144

__global__ __launch_bounds__(512, 2) void attn_kernel(
    const u16* __restrict__ Q, const u16* __restrict__ K,
    const u16* __restrict__ Vt, u16* __restrict__ Y)
{
    extern __shared__ __align__(16) u16 asmem[];
    int t = threadIdx.x;
    int w = t >> 6, lane = t & 63;
    int m = lane & 15, quad = lane >> 4;
    int iq = w >> 1, kh = w & 1;         // q-slice 0..3 (32 rows each), kv-half 0..1

    int bid = blockIdx.x;
    int head = bid & 31;                 // head%8 = bid%8 -> XCD affinity
    int g = bid >> 5;                    // 0..15
    int qb = (g < 8) ? g : 23 - g;       // q-block 0..15; co-resident pair sums 15
    int lim = 2 * qb + 1;                // last kv-chunk index (chunks of 64)
    int rb = qb * 128 + iq * 32;         // wave's first q-row

    const u16* qp0 = Q + ((size_t)head * TT + rb + m) * HDD + quad * 8;
    const u16* qp1 = Q + ((size_t)head * TT + rb + 16 + m) * HDD + quad * 8;
    bf16x8 q00 = *(const bf16x8*)qp0;
    bf16x8 q01 = *(const bf16x8*)(qp0 + 32);
    bf16x8 q10 = *(const bf16x8*)qp1;
    bf16x8 q11 = *(const bf16x8*)(qp1 + 32);

    // bf16 1.0 = 0x3F80 in every element (A-operand for the l row-sum MFMA)
    bf16x8 ones;
#pragma unroll
    for (int i = 0; i < 8; ++i) ones[i] = (short)0x3F80;

    const u16* kbase = K + (size_t)head * TT * HDD;   // [t][d]
    const u16* vbase = Vt + (size_t)head * HDD * TT;  // [d][t]
    u16* pb0 = asmem + 24576 + (w * 2 + 0) * (16 * PST2);
    u16* pb1 = asmem + 24576 + (w * 2 + 1) * (16 * PST2);

    // staging geometry: each of 8 waves stages 8 K-rows + 8 V-rows
    int lr = lane >> 3;
    int cg = (lane & 7) ^ lr;            // XOR swizzle on global col-group
    int r0 = w * 8 + lr;                 // 0..63
    int loff = (w * 64 + lane) * 8;      // u16 offset within one 4096-u16 buffer

    f32x4 zero = {0.f, 0.f, 0.f, 0.f};
    f32x4 o0[4], o1[4], la0 = zero, la1 = zero;
#pragma unroll
    for (int dg = 0; dg < 4; ++dg) { o0[dg] = zero; o1[dg] = zero; }
    int qc0 = rb + m, qc1 = rb + 16 + m;
    int sw = m & 7;

    // pointer-bump staging sources (advance once per prefetch)
    const u16* kst = kbase + (size_t)r0 * 64 + cg * 8;   // K rows: +64*HDD/chunk
    const u16* vst = vbase + (size_t)r0 * TT + cg * 8;   // V cols: +64/chunk

    // prologue: stage chunk 0 -> buf0, chunk 1 -> buf1 (4 loads in flight)
    async_copy16(kst, asmem + loff);
    async_copy16(vst, asmem + 12288 + loff);
    kst += 64 * HDD; vst += 64;
    async_copy16(kst, asmem + 4096 + loff);
    async_copy16(vst, asmem + 16384 + loff);
    kst += 64 * HDD; vst += 64;

// chunk compute: hoist kf/vf once, share across both q-subtiles.
// order: qk(s0) -> pf0 -> qk(s1) -> pv(s0) -> pf1 -> pv(s1)  (P-roundtrip
// latency hidden under the other subtile's MFMA+exp issue).
// T5: setprio(1) across the compute cluster.
#define ATTN_CHUNK(KBUF, VBUF, IC) do {                                             \
    int kvb_ = ((IC) << 6) + kh * 32;                                               \
    bool msk_ = (IC) >= 2 * qb;                                                     \
    bf16x8 kf_[2][2], vf_[4];                                                       \
    _Pragma("unroll") for (int kc_ = 0; kc_ < 2; ++kc_) {                           \
        int rr_ = kh * 32 + kc_ * 16 + m;                                           \
        kf_[kc_][0] = *(const bf16x8*)&(KBUF)[rr_ * 64 + ((quad ^ sw) << 3)];       \
        kf_[kc_][1] = *(const bf16x8*)&(KBUF)[rr_ * 64 + (((quad + 4) ^ sw) << 3)]; \
    }                                                                               \
    _Pragma("unroll") for (int dg_ = 0; dg_ < 4; ++dg_) {                           \
        int rr_ = dg_ * 16 + m;                                                     \
        vf_[dg_] = *(const bf16x8*)&(VBUF)[rr_ * 64 + (((kh * 4 + quad) ^ sw) << 3)]; \
    }                                                                               \
    __builtin_amdgcn_s_setprio(1);                                                  \
    if (msk_) tile_qk2<true >(kf_, pb0, q00, q01, m, quad, kvb_, qc0);              \
    else      tile_qk2<false>(kf_, pb0, q00, q01, m, quad, kvb_, qc0);              \
    bf16x8 pf0_ = load_pf(pb0, m, quad);                                            \
    if (msk_) tile_qk2<true >(kf_, pb1, q10, q11, m, quad, kvb_, qc1);              \
    else      tile_qk2<false>(kf_, pb1, q10, q11, m, quad, kvb_, qc1);              \
    tile_pv2(vf_, pf0_, ones, o0, la0);                                             \
    bf16x8 pf1_ = load_pf(pb1, m, quad);                                            \
    tile_pv2(vf_, pf1_, ones, o1, la1);                                             \
    __builtin_amdgcn_s_setprio(0);                                                  \
  } while (0)

// one chunk body: counted-vmcnt wait (chunk IC's 2 loads are the oldest of 4
// outstanding when IC<lim; only 2 outstanding at IC==lim -> drain), raw
// barrier, prefetch chunk IC+2 into the rotation buffer, compute chunk IC.
// lgkmcnt(0) before the barrier = WAR fence for the prefetch overwrite.
#define ATTN_BODY(IC, KBUF, VBUF, PKBUF, PVBUF) do {                                \
    if ((IC) < lim) asm volatile("s_waitcnt vmcnt(2) lgkmcnt(0)" ::: "memory");     \
    else            asm volatile("s_waitcnt vmcnt(0) lgkmcnt(0)" ::: "memory");     \
    __builtin_amdgcn_s_barrier();                                                   \
    asm volatile("" ::: "memory");                                                  \
    if ((IC) + 2 <= lim) {                                                          \
        async_copy16(kst, (PKBUF) + loff);                                          \
        async_copy16(vst, (PVBUF) + loff);                                          \
        kst += 64 * HDD; vst += 64;                                                 \
    }                                                                               \
    ATTN_CHUNK(KBUF, VBUF, IC);                                                     \
  } while (0)

    int ic = 0;
    // triple-unrolled rotation: chunk c lives in buf c%3 (compile-time bases)
    while (ic + 2 <= lim) {
        ATTN_BODY(ic,     asmem,        asmem + 12288, asmem + 8192, asmem + 20480);
        ATTN_BODY(ic + 1, asmem + 4096, asmem + 16384, asmem,        asmem + 12288);
        ATTN_BODY(ic + 2, asmem + 8192, asmem + 20480, asmem + 4096, asmem + 16384);
        ic += 3;
    }
    if (ic <= lim) {           // tail chunk in buf0 (no prefetch: ic+2 > lim)
        ATTN_BODY(ic, asmem, asmem + 12288, asmem + 8192, asmem + 20480);
        ++ic;
    }
    if (ic <= lim) {           // tail chunk in buf1
        ATTN_BODY(ic, asmem + 4096, asmem + 16384, asmem, asmem + 12288);
        ++ic;
    }
#undef ATTN_BODY
#undef ATTN_CHUNK

    // l fully reduced over this wave's kv-half (MFMA k-reduction):
    // every lane holds l for q=lane&15 in every lacc reg.
    float l0 = la0[0];
    float l1 = la1[0];

    // cross-kh combine: kh=1 writes O-partials + l, kh=0 merges & stores
    __syncthreads();
    f32x4* ob = (f32x4*)asmem;                // 32KB overlay on K/V buffers
    float* lb = (float*)&asmem[34816];        // 128 floats
    if (kh) {
        f32x4* dst = ob + (size_t)iq * 512 + lane;
#pragma unroll
        for (int dg = 0; dg < 4; ++dg) {
            dst[dg * 64] = o0[dg];
            dst[(4 + dg) * 64] = o1[dg];
        }
        if (quad == 0) {
            lb[(iq * 2 + 0) * 16 + m] = l0;
            lb[(iq * 2 + 1) * 16 + m] = l1;
        }
    }
    __syncthreads();
    if (!kh) {
        f32x4* src = ob + (size_t)iq * 512 + lane;
#pragma unroll
        for (int dg = 0; dg < 4; ++dg) {
            o0[dg] += src[dg * 64];
            o1[dg] += src[(4 + dg) * 64];
        }
        l0 += lb[(iq * 2 + 0) * 16 + m];
        l1 += lb[(iq * 2 + 1) * 16 + m];
        float inv0 = 1.0f / l0, inv1 = 1.0f / l1;

        int b = head >> 4, h = head & 15;
        size_t ro0 = ((size_t)(b * TT + rb + m)) * CCH + h * HDD;
        size_t ro1 = ((size_t)(b * TT + rb + 16 + m)) * CCH + h * HDD;
#pragma unroll
        for (int dg = 0; dg < 4; ++dg) {
            uint2 ov;
            ov.x = pk_bf16(o0[dg][0] * inv0, o0[dg][1] * inv0);
            ov.y = pk_bf16(o0[dg][2] * inv0, o0[dg][3] * inv0);
            *(uint2*)&Y[ro0 + dg * 16 + quad * 4] = ov;
            ov.x = pk_bf16(o1[dg][0] * inv1, o1[dg][1] * inv1);
            ov.y = pk_bf16(o1[dg][2] * inv1, o1[dg][3] * inv1);
            *(uint2*)&Y[ro1 + dg * 16 + quad * 4] = ov;
        }
    }
}

// ---------------- launch ----------------

extern "C" void kernel_launch(void* const* d_in, const int* in_sizes, int n_in,
                              void* d_out, int out_size, void* d_ws, size_t ws_size,
                              hipStream_t stream) {
    const float* x      = (const float*)d_in[0];
    const float* w_attn = (const float*)d_in[1];
    const float* w_proj = (const float*)d_in[2];
    float* out = (float*)d_out;

    char* ws = (char*)d_ws;
    u16* x_bf   = (u16*)ws; ws += (size_t)M_TOK * CCH * 2;         // 8 MB
    u16* wqkvT  = (u16*)ws; ws += (size_t)N_QKV * CCH * 2;         // 6 MB
    u16* wprojT = (u16*)ws; ws += (size_t)CCH * CCH * 2;           // 2 MB
    u16* qbuf   = (u16*)ws; ws += (size_t)BB * NHH * TT * HDD * 2; // 8 MB
    u16* kbuf   = (u16*)ws; ws += (size_t)BB * NHH * TT * HDD * 2; // 8 MB
    u16* vtb    = (u16*)ws; ws += (size_t)BB * NHH * HDD * TT * 2; // 8 MB
    u16* yb     = (u16*)ws; ws += (size_t)M_TOK * CCH * 2;         // 8 MB

    // one-time: allow big dynamic LDS for the pipelined kernels (host-side)
    static bool attr_done = false;
    if (!attr_done) {
        (void)hipFuncSetAttribute(reinterpret_cast<const void*>(qkv_gemm_kernel),
                                  hipFuncAttributeMaxDynamicSharedMemorySize,
                                  QKV_SMEM_BYTES);
        (void)hipFuncSetAttribute(reinterpret_cast<const void*>(proj_gemm_kernel),
                                  hipFuncAttributeMaxDynamicSharedMemorySize,
                                  PRJ_SMEM_BYTES);
        (void)hipFuncSetAttribute(reinterpret_cast<const void*>(attn_kernel),
                                  hipFuncAttributeMaxDynamicSharedMemorySize,
                                  ATTN_SMEM_BYTES);
        attr_done = true;
    }

    // 1+2. merged pre-pass: cast x + transpose both weight matrices (1 dispatch)
    prepass_kernel<<<dim3(8192), dim3(256), 0, stream>>>(
        x, w_attn, w_proj, x_bf, wqkvT, wprojT);
    // 3. QKV GEMM v2: 256 blocks (1/CU), 256x192 tiles, counted-vmcnt pipeline
    qkv_gemm_kernel<<<dim3(16, 16), dim3(512), QKV_SMEM_BYTES, stream>>>(
        x_bf, wqkvT, qbuf, kbuf, vtb);
    // 4. flash attention v20 (v19 + T5 setprio)
    attn_kernel<<<dim3(512), dim3(512), ATTN_SMEM_BYTES, stream>>>(qbuf, kbuf, vtb, yb);
    // 5. proj GEMM v2: 256 blocks (1/CU), 128x128 tiles, counted-vmcnt pipeline
    proj_gemm_kernel<<<dim3(8, 32), dim3(512), PRJ_SMEM_BYTES, stream>>>(
        yb, wprojT, out);
}